// Round 6
// baseline (453.486 us; speedup 1.0000x reference)
//
#include <hip/hip_runtime.h>

#define BB 128
#define TT 512
#define CC 128

typedef short short8 __attribute__((ext_vector_type(8)));
typedef float f32x4  __attribute__((ext_vector_type(4)));

__device__ __forceinline__ unsigned pk_trunc(float a, float b) {
    // lo16 = trunc-bf16(a), hi16 = trunc-bf16(b); single v_perm (R5-verified)
    return __builtin_amdgcn_perm(__float_as_uint(a), __float_as_uint(b), 0x03020706u);
}
__device__ __forceinline__ unsigned short f2bf(float f) {   // RNE (E setup only)
    unsigned u = __float_as_uint(f);
    u += 0x7fffu + ((u >> 16) & 1u);
    return (unsigned short)(u >> 16);
}
__device__ __forceinline__ float lo16f(unsigned u) { return __uint_as_float(u << 16); }
__device__ __forceinline__ float hi16f(unsigned u) { return __uint_as_float(u & 0xffff0000u); }

__device__ __forceinline__ void dma16(const void* g, void* l) {
    __builtin_amdgcn_global_load_lds(
        (const __attribute__((address_space(1))) unsigned int*)g,
        (__attribute__((address_space(3))) unsigned int*)l, 16, 0, 0);
}

// ---------------------------------------------------------------------------
// Kernel 1: fused prep + real-path (both memory-bound streaming).
// Blocks [0,4096): prep — ws[(g*512+t)*512 + c*64 + lane] (float4) =
//   exp(y_pred*mask) in the scan's DMA lane order; masked steps (t>0, m<=0)
//   written as -1.0 sentinel so the scan needs NO separate mask channel.
// Blocks [4096,5120): real-path score waves (8 per batch), atomicAdd(-score).
// ---------------------------------------------------------------------------
__global__ __launch_bounds__(64) void crf_prep_real(
    const float* __restrict__ y_true, const float* __restrict__ y_pred,
    const float* __restrict__ mask, const float* __restrict__ trans,
    float4* __restrict__ ws, float* __restrict__ out)
{
    const int lane = threadIdx.x;

    if (blockIdx.x < 4096) {
        const int blk = blockIdx.x;
        const int g = blk >> 9, t = blk & 511;
        const int bq = lane & 15, q = lane >> 4;
        const int b = g * 16 + bq;
        const float m = mask[(size_t)b * TT + t];
        const bool live = (m > 0.f) || (t == 0);   // t=0 init never keeps-old
        const float* row = y_pred + ((size_t)b * TT + t) * CC;
        float4* dst = ws + ((size_t)(g * 512 + t) * 512) + lane;
        #pragma unroll
        for (int c = 0; c < 8; ++c) {
            const int j0 = (c >> 1) * 32 + q * 8 + (c & 1) * 4;
            float4 v = *(const float4*)(row + j0);
            float4 r;
            if (live) {
                r.x = __expf(v.x * m); r.y = __expf(v.y * m);
                r.z = __expf(v.z * m); r.w = __expf(v.w * m);
            } else {
                r.x = r.y = r.z = r.w = -1.0f;
            }
            dst[c * 64] = r;
        }
        return;
    }

    // ===================== real path (R3/R4/R5-verified) =====================
    const int rbw = blockIdx.x - 4096;
    const int rb  = rbw >> 3;
    const int w   = rbw & 7;
    const int ts  = w * 64;
    const int te  = min(ts + 64, TT - 1);
    const float* yt_b = y_true + (size_t)rb * TT * CC;
    const float* yp_b = y_pred + (size_t)rb * TT * CC;
    const float* m_b  = mask + (size_t)rb * TT;

    float em = 0.f, tr = 0.f;
    int lprev = 0; float mprev = 0.f;
    const float* ytr = yt_b + ts * CC;
    const float* ypr = yp_b + ts * CC;
    float cyt0 = ytr[lane], cyt1 = ytr[lane + 64];
    float cyp0 = ypr[lane], cyp1 = ypr[lane + 64];
    float cm = m_b[ts];
    for (int t = ts; t <= te; ++t) {
        float nyt0 = 0.f, nyt1 = 0.f, nyp0 = 0.f, nyp1 = 0.f, nm = 0.f;
        if (t < te) {
            const float* ytn = yt_b + (t + 1) * CC;
            const float* ypn = yp_b + (t + 1) * CC;
            nyt0 = ytn[lane]; nyt1 = ytn[lane + 64];
            nyp0 = ypn[lane]; nyp1 = ypn[lane + 64];
            nm = m_b[t + 1];
        }
        unsigned long long b0 = __ballot(cyt0 > 0.5f);
        unsigned long long b1 = __ballot(cyt1 > 0.5f);
        int l = b0 ? (__ffsll(b0) - 1) : (64 + __ffsll(b1) - 1);
        float v0 = __shfl(cyp0, l & 63);
        float v1 = __shfl(cyp1, l & 63);
        float v  = (l < 64) ? v0 : v1;
        if (lane == 0) {
            if (t < ts + 64) em += cm * cm * v;
            if (t > ts)      tr += mprev * cm * trans[lprev * CC + l];
        }
        lprev = l; mprev = cm;
        cyt0 = nyt0; cyt1 = nyt1; cyp0 = nyp0; cyp1 = nyp1; cm = nm;
    }
    if (lane == 0) atomicAdd(&out[rb], -(em + tr));
}

// ---------------------------------------------------------------------------
// Kernel 2: in-register MFMA scan with LDS-DMA pipelined e-stream.
// 8 blocks x 1 wave; ring of 8 step-slots (8 KB each) in LDS filled by
// global_load_lds; manual s_waitcnt vmcnt(N) keeps 4 steps in flight.
// ---------------------------------------------------------------------------
__global__ __launch_bounds__(64, 1) void crf_scan(
    const float* __restrict__ trans, const float4* __restrict__ ws,
    float* __restrict__ out)
{
    __shared__ __align__(16) float ring[8][2048];   // 64 KB
    const int lane = threadIdx.x;
    const int g    = blockIdx.x;
    const int bq   = lane & 15;
    const int q    = lane >> 4;

    // A-frags: Af[nt][kt] = E^T tile with row perm sigma (R4-verified).
    short8 Af[8][4];
    #pragma unroll
    for (int nt = 0; nt < 8; ++nt) {
        const int j = 32 * (nt & 3) + 8 * (bq >> 2) + 4 * (nt >> 2) + (bq & 3);
        #pragma unroll
        for (int kt = 0; kt < 4; ++kt) {
            #pragma unroll
            for (int e = 0; e < 8; ++e)
                Af[nt][kt][e] = (short)f2bf(__expf(trans[(kt * 32 + q * 8 + e) * CC + j]));
        }
    }

    const float4* wsg = ws + (size_t)g * (TT * 512) + lane;

    // prologue: DMA steps 0..5 into slots 0..5 (48 outstanding)
    #pragma unroll
    for (int t = 0; t < 6; ++t) {
        const float4* gp = wsg + t * 512;
        #pragma unroll
        for (int c = 0; c < 8; ++c)
            dma16(gp + c * 64, &ring[t][c * 256]);
    }

    float4 E0[8], E1[8];
    float pend = 1.f, lacc = 0.f;
    unsigned ps[16];        // packed bf16 state = next-step B-fragments

    asm volatile("s_waitcnt vmcnt(40)" ::: "memory");   // slot 0 ready
    #pragma unroll
    for (int c = 0; c < 8; ++c)
        E0[c] = *(const float4*)&ring[0][c * 256 + lane * 4];
    #pragma unroll
    for (int c = 0; c < 8; ++c) {                       // t=0 init: S0 = e(0)
        const int kt = c >> 1, h = c & 1;
        ps[kt * 4 + 2 * h + 0] = pk_trunc(E0[c].x, E0[c].y);
        ps[kt * 4 + 2 * h + 1] = pk_trunc(E0[c].z, E0[c].w);
    }
    asm volatile("s_waitcnt vmcnt(32)" ::: "memory");   // slot 1 ready
    #pragma unroll
    for (int c = 0; c < 8; ++c)
        E1[c] = *(const float4*)&ring[1][c * 256 + lane * 4];

#define STEP(T, DMAEN, WN, AP, RN, EC, EN)                                        \
    do {                                                                          \
        if (DMAEN) {                                                              \
            const float4* gp_ = wsg + ((T) + 5) * 512;                            \
            _Pragma("unroll")                                                     \
            for (int c = 0; c < 8; ++c)                                           \
                dma16(gp_ + c * 64, &ring[((T) + 5) & 7][c * 256]);               \
        }                                                                         \
        asm volatile("s_waitcnt vmcnt(%0)" :: "n"(WN) : "memory");                \
        if ((T) < TT - 1) {                                                       \
            _Pragma("unroll")                                                     \
            for (int c = 0; c < 8; ++c)                                           \
                EN[c] = *(const float4*)&ring[((T) + 1) & 7][c * 256 + lane * 4]; \
        }                                                                         \
        short8 Bf[4];                                                             \
        _Pragma("unroll")                                                         \
        for (int kt = 0; kt < 4; ++kt) {                                          \
            union { unsigned u[4]; short8 s; } bu_;                               \
            bu_.u[0] = ps[kt * 4 + 0]; bu_.u[1] = ps[kt * 4 + 1];                 \
            bu_.u[2] = ps[kt * 4 + 2]; bu_.u[3] = ps[kt * 4 + 3];                 \
            Bf[kt] = bu_.s;                                                       \
        }                                                                         \
        f32x4 acc[8];                                                             \
        _Pragma("unroll")                                                         \
        for (int nt = 0; nt < 8; ++nt) {                                          \
            f32x4 a = {0.f, 0.f, 0.f, 0.f};                                       \
            a = __builtin_amdgcn_mfma_f32_16x16x32_bf16(Af[nt][0], Bf[0], a, 0, 0, 0); \
            a = __builtin_amdgcn_mfma_f32_16x16x32_bf16(Af[nt][1], Bf[1], a, 0, 0, 0); \
            a = __builtin_amdgcn_mfma_f32_16x16x32_bf16(Af[nt][2], Bf[2], a, 0, 0, 0); \
            a = __builtin_amdgcn_mfma_f32_16x16x32_bf16(Af[nt][3], Bf[3], a, 0, 0, 0); \
            acc[nt] = a;                                                          \
        }                                                                         \
        const float mv_ = EC[0].x;          /* -1 sentinel = masked step */       \
        float val[8][4];                                                          \
        _Pragma("unroll")                                                         \
        for (int nt = 0; nt < 8; ++nt) {                                          \
            const int c_ = 2 * (nt & 3) + (nt >> 2);                              \
            val[nt][0] = acc[nt][0] * EC[c_].x; val[nt][1] = acc[nt][1] * EC[c_].y; \
            val[nt][2] = acc[nt][2] * EC[c_].z; val[nt][3] = acc[nt][3] * EC[c_].w; \
            if (AP) {                                                             \
                val[nt][0] *= pend; val[nt][1] *= pend;                           \
                val[nt][2] *= pend; val[nt][3] *= pend;                           \
            }                                                                     \
        }                                                                         \
        unsigned nps[16];                                                         \
        _Pragma("unroll")                                                         \
        for (int nt = 0; nt < 8; ++nt) {                                          \
            const int kt = nt & 3, h = nt >> 2;                                   \
            nps[kt * 4 + 2 * h + 0] = pk_trunc(val[nt][0], val[nt][1]);           \
            nps[kt * 4 + 2 * h + 1] = pk_trunc(val[nt][2], val[nt][3]);           \
        }                                                                         \
        if (__ballot(mv_ < 0.f)) {                                                \
            _Pragma("unroll")                                                     \
            for (int p = 0; p < 16; ++p) {                                        \
                unsigned kept = pk_trunc(lo16f(ps[p]) * pend, hi16f(ps[p]) * pend); \
                nps[p] = (mv_ < 0.f) ? kept : nps[p];                             \
            }                                                                     \
        }                                                                         \
        _Pragma("unroll")                                                         \
        for (int p = 0; p < 16; ++p) ps[p] = nps[p];                              \
        if (AP) pend = 1.f;                                                       \
        if (RN) {                                                                 \
            float s_  = lo16f(ps[0]);                                             \
            float bc_ = __shfl(s_, bq, 64);                                       \
            pend = __builtin_amdgcn_rcpf(bc_);                                    \
            lacc += __logf(bc_);                                                  \
        }                                                                         \
    } while (0)

    // main: t = 1..504 (DMA t+5 <= 509 always valid; ring distance 5, allow 4
    // newer 8-DMA batches outstanding -> vmcnt(32))
    for (int k = 0; k < 63; ++k) {
        const int t0 = 8 * k + 1;
        STEP(t0 + 0, 1, 32, true,  false, E1, E0);
        STEP(t0 + 1, 1, 32, false, false, E0, E1);
        STEP(t0 + 2, 1, 32, false, false, E1, E0);
        STEP(t0 + 3, 1, 32, false, true,  E0, E1);
        STEP(t0 + 4, 1, 32, true,  false, E1, E0);
        STEP(t0 + 5, 1, 32, false, false, E0, E1);
        STEP(t0 + 6, 1, 32, false, false, E1, E0);
        STEP(t0 + 7, 1, 32, false, true,  E0, E1);
    }
    // peel t = 505..510 (DMA stops at 511; waitcnt tightens as queue drains)
    STEP(505, 1, 32, true,  false, E1, E0);
    STEP(506, 1, 32, false, false, E0, E1);
    STEP(507, 0, 24, false, false, E1, E0);
    STEP(508, 0, 16, false, true,  E0, E1);
    STEP(509, 0,  8, true,  false, E1, E0);
    STEP(510, 0,  0, false, false, E0, E1);

    // -------- final step t = 511 (EC = E1): sum instead of pack --------
    {
        short8 Bf[4];
        #pragma unroll
        for (int kt = 0; kt < 4; ++kt) {
            union { unsigned u[4]; short8 s; } bu;
            bu.u[0] = ps[kt * 4 + 0]; bu.u[1] = ps[kt * 4 + 1];
            bu.u[2] = ps[kt * 4 + 2]; bu.u[3] = ps[kt * 4 + 3];
            Bf[kt] = bu.s;
        }
        float ssum = 0.f;
        const float mv = E1[0].x;
        #pragma unroll
        for (int nt = 0; nt < 8; ++nt) {
            f32x4 a = {0.f, 0.f, 0.f, 0.f};
            a = __builtin_amdgcn_mfma_f32_16x16x32_bf16(Af[nt][0], Bf[0], a, 0, 0, 0);
            a = __builtin_amdgcn_mfma_f32_16x16x32_bf16(Af[nt][1], Bf[1], a, 0, 0, 0);
            a = __builtin_amdgcn_mfma_f32_16x16x32_bf16(Af[nt][2], Bf[2], a, 0, 0, 0);
            a = __builtin_amdgcn_mfma_f32_16x16x32_bf16(Af[nt][3], Bf[3], a, 0, 0, 0);
            const int c = 2 * (nt & 3) + (nt >> 2);
            ssum += a[0] * E1[c].x + a[1] * E1[c].y + a[2] * E1[c].z + a[3] * E1[c].w;
        }
        if (__ballot(mv < 0.f)) {
            float os = 0.f;
            #pragma unroll
            for (int p = 0; p < 16; ++p) os += lo16f(ps[p]) + hi16f(ps[p]);
            ssum = (mv < 0.f) ? os : ssum;   // pend == 1 here (511 % 4 == 3)
        }
        ssum += __shfl_xor(ssum, 16, 64);
        ssum += __shfl_xor(ssum, 32, 64);
        if (lane < 16) atomicAdd(&out[g * 16 + lane], __logf(ssum) + lacc);
    }
#undef STEP
}

// ---------------------------------------------------------------------------
// Fallback scan (only if ws too small): R4-verified direct-load variant.
// ---------------------------------------------------------------------------
__global__ __launch_bounds__(64, 1) void crf_scan_direct(
    const float* __restrict__ y_pred, const float* __restrict__ mask,
    const float* __restrict__ trans, float* __restrict__ out)
{
    const int lane = threadIdx.x;
    const int g  = blockIdx.x;
    const int bq = lane & 15;
    const int q  = lane >> 4;

    short8 Af[8][4];
    #pragma unroll
    for (int nt = 0; nt < 8; ++nt) {
        const int j = 32 * (nt & 3) + 8 * (bq >> 2) + 4 * (nt >> 2) + (bq & 3);
        #pragma unroll
        for (int kt = 0; kt < 4; ++kt)
            #pragma unroll
            for (int e = 0; e < 8; ++e)
                Af[nt][kt][e] = (short)f2bf(__expf(trans[(kt * 32 + q * 8 + e) * CC + j]));
    }
    const float* yaddr[8];
    {
        const float* ybase = y_pred + (size_t)(g * 16 + bq) * TT * CC;
        #pragma unroll
        for (int c = 0; c < 8; ++c)
            yaddr[c] = ybase + ((c >> 1) * 32 + q * 8 + (c & 1) * 4);
    }
    const float* mrow = mask + (size_t)(g * 16 + bq) * TT;

    float4 eb0[8], eb1[8]; float mb0, mb1;
    auto loadE = [&](int t, float4 (&buf)[8], float& mv) {
        #pragma unroll
        for (int c = 0; c < 8; ++c)
            buf[c] = *(const float4*)(yaddr[c] + (size_t)t * CC);
        mv = mrow[t];
    };
    auto getE = [&](const float4& raw, float mv) -> float4 {
        float4 r;
        r.x = __expf(raw.x * mv); r.y = __expf(raw.y * mv);
        r.z = __expf(raw.z * mv); r.w = __expf(raw.w * mv);
        return r;
    };

    float pend = 1.f, lacc = 0.f;
    unsigned ps[16];
    loadE(0, eb0, mb0);
    #pragma unroll
    for (int c = 0; c < 8; ++c) {
        float4 e0 = getE(eb0[c], mb0);
        const int kt = c >> 1, h = c & 1;
        ps[kt * 4 + 2 * h + 0] = pk_trunc(e0.x, e0.y);
        ps[kt * 4 + 2 * h + 1] = pk_trunc(e0.z, e0.w);
    }
    loadE(1, eb1, mb1);

    for (int t = 1; t < TT; ++t) {
        float4 (&EC)[8] = (t & 1) ? eb1 : eb0;
        float4 (&EN)[8] = (t & 1) ? eb0 : eb1;
        float   mv      = (t & 1) ? mb1 : mb0;
        short8 Bf[4];
        #pragma unroll
        for (int kt = 0; kt < 4; ++kt) {
            union { unsigned u[4]; short8 s; } bu;
            bu.u[0] = ps[kt * 4 + 0]; bu.u[1] = ps[kt * 4 + 1];
            bu.u[2] = ps[kt * 4 + 2]; bu.u[3] = ps[kt * 4 + 3];
            Bf[kt] = bu.s;
        }
        f32x4 acc[8];
        #pragma unroll
        for (int nt = 0; nt < 8; ++nt) {
            f32x4 a = {0.f, 0.f, 0.f, 0.f};
            a = __builtin_amdgcn_mfma_f32_16x16x32_bf16(Af[nt][0], Bf[0], a, 0, 0, 0);
            a = __builtin_amdgcn_mfma_f32_16x16x32_bf16(Af[nt][1], Bf[1], a, 0, 0, 0);
            a = __builtin_amdgcn_mfma_f32_16x16x32_bf16(Af[nt][2], Bf[2], a, 0, 0, 0);
            a = __builtin_amdgcn_mfma_f32_16x16x32_bf16(Af[nt][3], Bf[3], a, 0, 0, 0);
            acc[nt] = a;
        }
        if (t < TT - 1) {
            if (t & 1) loadE(t + 1, eb0, mb0); else loadE(t + 1, eb1, mb1);
        }
        const bool AP = ((t & 3) == 1);
        float val[8][4];
        #pragma unroll
        for (int nt = 0; nt < 8; ++nt) {
            const int c = 2 * (nt & 3) + (nt >> 2);
            float4 e = getE(EC[c], mv);
            val[nt][0] = acc[nt][0] * e.x; val[nt][1] = acc[nt][1] * e.y;
            val[nt][2] = acc[nt][2] * e.z; val[nt][3] = acc[nt][3] * e.w;
            if (AP) { val[nt][0] *= pend; val[nt][1] *= pend;
                      val[nt][2] *= pend; val[nt][3] *= pend; }
        }
        if (t == TT - 1) {   // final: sum
            float ssum = 0.f;
            #pragma unroll
            for (int nt = 0; nt < 8; ++nt)
                ssum += val[nt][0] + val[nt][1] + val[nt][2] + val[nt][3];
            if (__ballot(mv <= 0.f)) {
                float os = 0.f;
                #pragma unroll
                for (int p = 0; p < 16; ++p) os += lo16f(ps[p]) + hi16f(ps[p]);
                ssum = (mv <= 0.f) ? os : ssum;
            }
            ssum += __shfl_xor(ssum, 16, 64);
            ssum += __shfl_xor(ssum, 32, 64);
            if (lane < 16) atomicAdd(&out[g * 16 + lane], __logf(ssum) + lacc);
            break;
        }
        unsigned nps[16];
        #pragma unroll
        for (int nt = 0; nt < 8; ++nt) {
            const int kt = nt & 3, h = nt >> 2;
            nps[kt * 4 + 2 * h + 0] = pk_trunc(val[nt][0], val[nt][1]);
            nps[kt * 4 + 2 * h + 1] = pk_trunc(val[nt][2], val[nt][3]);
        }
        if (__ballot(mv <= 0.f)) {
            #pragma unroll
            for (int p = 0; p < 16; ++p) {
                unsigned kept = pk_trunc(lo16f(ps[p]) * pend, hi16f(ps[p]) * pend);
                nps[p] = (mv <= 0.f) ? kept : nps[p];
            }
        }
        #pragma unroll
        for (int p = 0; p < 16; ++p) ps[p] = nps[p];
        if (AP) pend = 1.f;
        if ((t & 3) == 0) {
            float s  = lo16f(ps[0]);
            float bc = __shfl(s, bq, 64);
            pend = __builtin_amdgcn_rcpf(bc);
            lacc += __logf(bc);
        }
    }
}

// ---------------------------------------------------------------------------
extern "C" void kernel_launch(void* const* d_in, const int* in_sizes, int n_in,
                              void* d_out, int out_size, void* d_ws, size_t ws_size,
                              hipStream_t stream) {
    (void)in_sizes; (void)n_in; (void)out_size;
    const float* y_true = (const float*)d_in[0];
    const float* y_pred = (const float*)d_in[1];
    const float* mask   = (const float*)d_in[2];
    const float* trans  = (const float*)d_in[3];
    float* out = (float*)d_out;

    const size_t need = (size_t)BB * TT * CC * sizeof(float);   // 32 MB
    hipMemsetAsync(out, 0, BB * sizeof(float), stream);
    crf_prep_real<<<4096 + BB * 8, 64, 0, stream>>>(
        y_true, y_pred, mask, trans, (float4*)d_ws, out);
    if (ws_size >= need)
        crf_scan<<<8, 64, 0, stream>>>(trans, (const float4*)d_ws, out);
    else
        crf_scan_direct<<<8, 64, 0, stream>>>(y_pred, mask, trans, out);
}

// Round 7
// 383.128 us; speedup vs baseline: 1.1836x; 1.1836x over previous
//
#include <hip/hip_runtime.h>

#define BB 128
#define TT 512
#define CC 128

typedef short short8 __attribute__((ext_vector_type(8)));
typedef float f32x4  __attribute__((ext_vector_type(4)));
typedef unsigned u32x4 __attribute__((ext_vector_type(4)));

__device__ __forceinline__ unsigned pk_trunc(float a, float b) {
    // lo16 = trunc-bf16(a), hi16 = trunc-bf16(b); single v_perm (R5-verified)
    return __builtin_amdgcn_perm(__float_as_uint(a), __float_as_uint(b), 0x03020706u);
}
__device__ __forceinline__ unsigned short f2bf(float f) {   // RNE (E setup only)
    unsigned u = __float_as_uint(f);
    u += 0x7fffu + ((u >> 16) & 1u);
    return (unsigned short)(u >> 16);
}
__device__ __forceinline__ float lo16f(unsigned u) { return __uint_as_float(u << 16); }
__device__ __forceinline__ float hi16f(unsigned u) { return __uint_as_float(u & 0xffff0000u); }

// ---------------------------------------------------------------------------
// Single fused kernel, 192 threads/block.
// Blocks 0..7   : scan. wave0 = MFMA consumer; waves1,2 = loader waves that
//                 stream exp(y_pred*mask) (bf16-packed, -1 sentinel when
//                 masked) into an 8-slot LDS ring with flag handshakes.
// Blocks 8..263 : real-path score; 2 blocks x 3 waves = 6 segments of 86 rows
//                 per batch; atomicAdd(-score) into out (zeroed by memset).
// ---------------------------------------------------------------------------
__global__ __launch_bounds__(192, 1) void crf_all(
    const float* __restrict__ y_true, const float* __restrict__ y_pred,
    const float* __restrict__ mask, const float* __restrict__ trans,
    float* __restrict__ out)
{
    __shared__ __align__(16) unsigned ring[8][1024];  // 32 KB: 8 slots x 4 KB
    __shared__ int flags[8];
    __shared__ int rcons;

    const int tid  = threadIdx.x;
    const int lane = tid & 63;
    const int w    = tid >> 6;

    if (blockIdx.x >= 8) {
        // ===================== real path (R3..R6-verified core) =============
        const int rbw = blockIdx.x - 8;       // 0..255
        const int rb  = rbw >> 1;
        const int seg = (rbw & 1) * 3 + w;    // 0..5
        const int ts  = seg * 86;
        const int te  = min(ts + 86, TT - 1);
        const float* yt_b = y_true + (size_t)rb * TT * CC;
        const float* yp_b = y_pred + (size_t)rb * TT * CC;
        const float* m_b  = mask + (size_t)rb * TT;

        float em = 0.f, tr = 0.f;
        int lprev = 0; float mprev = 0.f;
        const float* ytr = yt_b + ts * CC;
        const float* ypr = yp_b + ts * CC;
        float cyt0 = ytr[lane], cyt1 = ytr[lane + 64];
        float cyp0 = ypr[lane], cyp1 = ypr[lane + 64];
        float cm = m_b[ts];
        for (int t = ts; t <= te; ++t) {
            float nyt0 = 0.f, nyt1 = 0.f, nyp0 = 0.f, nyp1 = 0.f, nm = 0.f;
            if (t < te) {
                const float* ytn = yt_b + (t + 1) * CC;
                const float* ypn = yp_b + (t + 1) * CC;
                nyt0 = ytn[lane]; nyt1 = ytn[lane + 64];
                nyp0 = ypn[lane]; nyp1 = ypn[lane + 64];
                nm = m_b[t + 1];
            }
            unsigned long long b0 = __ballot(cyt0 > 0.5f);
            unsigned long long b1 = __ballot(cyt1 > 0.5f);
            int l = b0 ? (__ffsll(b0) - 1) : (64 + __ffsll(b1) - 1);
            float v0 = __shfl(cyp0, l & 63);
            float v1 = __shfl(cyp1, l & 63);
            float v  = (l < 64) ? v0 : v1;
            if (lane == 0) {
                if (t < ts + 86) em += cm * cm * v;
                if (t > ts)      tr += mprev * cm * trans[lprev * CC + l];
            }
            lprev = l; mprev = cm;
            cyt0 = nyt0; cyt1 = nyt1; cyp0 = nyp0; cyp1 = nyp1; cm = nm;
        }
        if (lane == 0) atomicAdd(&out[rb], -(em + tr));
        return;
    }

    // ========================== scan blocks ==========================
    volatile int* vflag = flags;
    volatile int* vrc   = &rcons;
    const int g  = blockIdx.x;
    const int bq = lane & 15;
    const int q  = lane >> 4;

    if (w == 0) {
        if (lane < 8)  vflag[lane] = -1;
        if (lane == 8) *vrc = -1;
    }
    __syncthreads();   // scan blocks only; all 192 threads reach

    if (w > 0) {
        // ========================== loader wave ==========================
        const int p = w - 1;                        // parity: steps t, t+2, ...
        const float* yad[8];
        {
            const float* ybase = y_pred + (size_t)(g * 16 + bq) * TT * CC;
            #pragma unroll
            for (int c = 0; c < 8; ++c)
                yad[c] = ybase + ((c >> 1) * 32 + q * 8 + (c & 1) * 4);
        }
        const float* mrow = mask + (size_t)(g * 16 + bq) * TT;

        float4 va[8], vb[8]; float ma, mb = 0.f;
        #pragma unroll
        for (int c = 0; c < 8; ++c) va[c] = *(const float4*)(yad[c] + p * CC);
        ma = mrow[p];

        for (int t = p; t < TT; t += 2) {
            const int tn = t + 2;
            if (tn < TT) {                          // depth-2 pipeline: issue next
                #pragma unroll
                for (int c = 0; c < 8; ++c)
                    vb[c] = *(const float4*)(yad[c] + (size_t)tn * CC);
                mb = mrow[tn];
            }
            while (*vrc < t - 8) __builtin_amdgcn_s_sleep(2);   // ring back-pressure
            const bool live = (ma > 0.f) || (t == 0);
            unsigned pu[16];
            #pragma unroll
            for (int c = 0; c < 8; ++c) {
                float ex, ey, ez, ew;
                if (live) {
                    ex = __expf(va[c].x * ma); ey = __expf(va[c].y * ma);
                    ez = __expf(va[c].z * ma); ew = __expf(va[c].w * ma);
                } else { ex = ey = ez = ew = -1.0f; }
                pu[2 * c + 0] = pk_trunc(ex, ey);
                pu[2 * c + 1] = pk_trunc(ez, ew);
            }
            unsigned* dst = &ring[t & 7][0];
            #pragma unroll
            for (int k = 0; k < 4; ++k) {
                u32x4 wv;
                wv[0] = pu[4 * k + 0]; wv[1] = pu[4 * k + 1];
                wv[2] = pu[4 * k + 2]; wv[3] = pu[4 * k + 3];
                *(u32x4*)(dst + k * 256 + lane * 4) = wv;
            }
            __atomic_signal_fence(__ATOMIC_SEQ_CST);  // order: data before flag
            vflag[t & 7] = t;                         // same-wave DS ops in order
            #pragma unroll
            for (int c = 0; c < 8; ++c) va[c] = vb[c];
            ma = mb;
        }
        return;
    }

    // ========================== consumer wave ==========================
    // A-frags: Af[nt][kt] = E^T tile with row perm sigma (R4-verified).
    short8 Af[8][4];
    #pragma unroll
    for (int nt = 0; nt < 8; ++nt) {
        const int j = 32 * (nt & 3) + 8 * (bq >> 2) + 4 * (nt >> 2) + (bq & 3);
        #pragma unroll
        for (int kt = 0; kt < 4; ++kt) {
            #pragma unroll
            for (int e = 0; e < 8; ++e)
                Af[nt][kt][e] = (short)f2bf(__expf(trans[(kt * 32 + q * 8 + e) * CC + j]));
        }
    }

    float pend = 1.f, lacc = 0.f;
    unsigned ps[16];          // packed bf16 state = next-step B-fragments
    u32x4 E0[4], E1[4];       // bf16-packed e(t) ping-pong (pu[j] = E[j>>2][j&3])

    // init: slot 0 = e(0) -> S0 (ring packing == ps packing, direct copy)
    while (vflag[0] != 0) __builtin_amdgcn_s_sleep(1);
    __atomic_signal_fence(__ATOMIC_SEQ_CST);
    #pragma unroll
    for (int k = 0; k < 4; ++k)
        E0[k] = *(const u32x4*)&ring[0][k * 256 + lane * 4];
    #pragma unroll
    for (int k = 0; k < 4; ++k) {
        ps[4 * k + 0] = E0[k][0]; ps[4 * k + 1] = E0[k][1];
        ps[4 * k + 2] = E0[k][2]; ps[4 * k + 3] = E0[k][3];
    }
    while (vflag[1] != 1) __builtin_amdgcn_s_sleep(1);
    __atomic_signal_fence(__ATOMIC_SEQ_CST);
    #pragma unroll
    for (int k = 0; k < 4; ++k)
        E1[k] = *(const u32x4*)&ring[1][k * 256 + lane * 4];

#define STEP(T, EC, EN, AP, RN)                                                   \
    do {                                                                          \
        const int s_ = ((T) + 1) & 7;                                             \
        int fv_ = vflag[s_];                     /* flag read BEFORE data reads */\
        __atomic_signal_fence(__ATOMIC_SEQ_CST);                                  \
        _Pragma("unroll")                                                         \
        for (int k = 0; k < 4; ++k)                                               \
            EN[k] = *(const u32x4*)&ring[s_][k * 256 + lane * 4];                 \
        short8 Bf[4];                                                             \
        _Pragma("unroll")                                                         \
        for (int kt = 0; kt < 4; ++kt) {                                          \
            union { unsigned u[4]; short8 s; } bu_;                               \
            bu_.u[0] = ps[kt * 4 + 0]; bu_.u[1] = ps[kt * 4 + 1];                 \
            bu_.u[2] = ps[kt * 4 + 2]; bu_.u[3] = ps[kt * 4 + 3];                 \
            Bf[kt] = bu_.s;                                                       \
        }                                                                         \
        f32x4 acc[8];                                                             \
        _Pragma("unroll")                                                         \
        for (int nt = 0; nt < 8; ++nt) {                                          \
            f32x4 a_ = {0.f, 0.f, 0.f, 0.f};                                      \
            a_ = __builtin_amdgcn_mfma_f32_16x16x32_bf16(Af[nt][0], Bf[0], a_, 0, 0, 0); \
            a_ = __builtin_amdgcn_mfma_f32_16x16x32_bf16(Af[nt][1], Bf[1], a_, 0, 0, 0); \
            a_ = __builtin_amdgcn_mfma_f32_16x16x32_bf16(Af[nt][2], Bf[2], a_, 0, 0, 0); \
            a_ = __builtin_amdgcn_mfma_f32_16x16x32_bf16(Af[nt][3], Bf[3], a_, 0, 0, 0); \
            acc[nt] = a_;                                                         \
        }                                                                         \
        if (fv_ != (T) + 1) {                    /* deferred check; rare path */  \
            while (vflag[s_] != (T) + 1) __builtin_amdgcn_s_sleep(1);             \
            __atomic_signal_fence(__ATOMIC_SEQ_CST);                              \
            _Pragma("unroll")                                                     \
            for (int k = 0; k < 4; ++k) {                                         \
                volatile const unsigned* rr_ = &ring[s_][k * 256 + lane * 4];     \
                u32x4 t_; t_[0] = rr_[0]; t_[1] = rr_[1];                         \
                t_[2] = rr_[2]; t_[3] = rr_[3];                                   \
                EN[k] = t_;                                                       \
            }                                                                     \
        }                                                                         \
        const float mv_ = lo16f(EC[0][0]);       /* sentinel: -1 = masked */      \
        float val[8][4];                                                          \
        _Pragma("unroll")                                                         \
        for (int nt = 0; nt < 8; ++nt) {                                          \
            const int c_ = 2 * (nt & 3) + (nt >> 2);                              \
            const unsigned plo_ = EC[(2 * c_) >> 2][(2 * c_) & 3];                \
            const unsigned phi_ = EC[(2 * c_ + 1) >> 2][(2 * c_ + 1) & 3];        \
            val[nt][0] = acc[nt][0] * lo16f(plo_);                                \
            val[nt][1] = acc[nt][1] * hi16f(plo_);                                \
            val[nt][2] = acc[nt][2] * lo16f(phi_);                                \
            val[nt][3] = acc[nt][3] * hi16f(phi_);                                \
            if (AP) {                                                             \
                val[nt][0] *= pend; val[nt][1] *= pend;                           \
                val[nt][2] *= pend; val[nt][3] *= pend;                           \
            }                                                                     \
        }                                                                         \
        unsigned nps[16];                                                         \
        _Pragma("unroll")                                                         \
        for (int nt = 0; nt < 8; ++nt) {                                          \
            const int kt = nt & 3, h = nt >> 2;                                   \
            nps[kt * 4 + 2 * h + 0] = pk_trunc(val[nt][0], val[nt][1]);           \
            nps[kt * 4 + 2 * h + 1] = pk_trunc(val[nt][2], val[nt][3]);           \
        }                                                                         \
        if (__ballot(mv_ < 0.f)) {                                                \
            _Pragma("unroll")                                                     \
            for (int p_ = 0; p_ < 16; ++p_) {                                     \
                unsigned kept = pk_trunc(lo16f(ps[p_]) * pend, hi16f(ps[p_]) * pend); \
                nps[p_] = (mv_ < 0.f) ? kept : nps[p_];                           \
            }                                                                     \
        }                                                                         \
        _Pragma("unroll")                                                         \
        for (int p_ = 0; p_ < 16; ++p_) ps[p_] = nps[p_];                         \
        if (AP) pend = 1.f;                                                       \
        if (RN) {                                                                 \
            float s2_ = lo16f(ps[0]);                                             \
            float bc_ = __shfl(s2_, bq, 64);                                      \
            pend = __builtin_amdgcn_rcpf(bc_);                                    \
            lacc += __logf(bc_);                                                  \
            *vrc = (T);                         /* publish consumed step */       \
        }                                                                         \
    } while (0)

    for (int k = 0; k < 127; ++k) {
        const int t0 = 4 * k + 1;
        STEP(t0,     E1, E0, true,  false);
        STEP(t0 + 1, E0, E1, false, false);
        STEP(t0 + 2, E1, E0, false, false);
        STEP(t0 + 3, E0, E1, false, true);
    }
    STEP(509, E1, E0, true,  false);    // reads slot 510
    STEP(510, E0, E1, false, false);    // reads slot 511

    // -------- final step t = 511 (EC = E1): sum instead of pack --------
    {
        short8 Bf[4];
        #pragma unroll
        for (int kt = 0; kt < 4; ++kt) {
            union { unsigned u[4]; short8 s; } bu;
            bu.u[0] = ps[kt * 4 + 0]; bu.u[1] = ps[kt * 4 + 1];
            bu.u[2] = ps[kt * 4 + 2]; bu.u[3] = ps[kt * 4 + 3];
            Bf[kt] = bu.s;
        }
        float ssum = 0.f;
        const float mv = lo16f(E1[0][0]);
        #pragma unroll
        for (int nt = 0; nt < 8; ++nt) {
            f32x4 a = {0.f, 0.f, 0.f, 0.f};
            a = __builtin_amdgcn_mfma_f32_16x16x32_bf16(Af[nt][0], Bf[0], a, 0, 0, 0);
            a = __builtin_amdgcn_mfma_f32_16x16x32_bf16(Af[nt][1], Bf[1], a, 0, 0, 0);
            a = __builtin_amdgcn_mfma_f32_16x16x32_bf16(Af[nt][2], Bf[2], a, 0, 0, 0);
            a = __builtin_amdgcn_mfma_f32_16x16x32_bf16(Af[nt][3], Bf[3], a, 0, 0, 0);
            const int c = 2 * (nt & 3) + (nt >> 2);
            const unsigned plo = E1[(2 * c) >> 2][(2 * c) & 3];
            const unsigned phi = E1[(2 * c + 1) >> 2][(2 * c + 1) & 3];
            ssum += a[0] * lo16f(plo) + a[1] * hi16f(plo)
                  + a[2] * lo16f(phi) + a[3] * hi16f(phi);
        }
        if (__ballot(mv < 0.f)) {
            float os = 0.f;
            #pragma unroll
            for (int p = 0; p < 16; ++p) os += lo16f(ps[p]) + hi16f(ps[p]);
            ssum = (mv < 0.f) ? os : ssum;   // pend == 1 here (511 % 4 == 3)
        }
        ssum += __shfl_xor(ssum, 16, 64);
        ssum += __shfl_xor(ssum, 32, 64);
        if (lane < 16) atomicAdd(&out[g * 16 + lane], __logf(ssum) + lacc);
    }
#undef STEP
}

// ---------------------------------------------------------------------------
extern "C" void kernel_launch(void* const* d_in, const int* in_sizes, int n_in,
                              void* d_out, int out_size, void* d_ws, size_t ws_size,
                              hipStream_t stream) {
    (void)in_sizes; (void)n_in; (void)out_size; (void)d_ws; (void)ws_size;
    const float* y_true = (const float*)d_in[0];
    const float* y_pred = (const float*)d_in[1];
    const float* mask   = (const float*)d_in[2];
    const float* trans  = (const float*)d_in[3];
    float* out = (float*)d_out;

    hipMemsetAsync(out, 0, BB * sizeof(float), stream);
    crf_all<<<dim3(8 + 2 * BB), 192, 0, stream>>>(y_true, y_pred, mask, trans, out);
}

// Round 8
// 317.760 us; speedup vs baseline: 1.4271x; 1.2057x over previous
//
#include <hip/hip_runtime.h>

#define BB 128
#define TT 512
#define CC 128

typedef short short8 __attribute__((ext_vector_type(8)));
typedef float f32x4  __attribute__((ext_vector_type(4)));
typedef unsigned u32x4 __attribute__((ext_vector_type(4)));

__device__ __forceinline__ unsigned pk_trunc(float a, float b) {
    // lo16 = trunc-bf16(a), hi16 = trunc-bf16(b); single v_perm (R5-verified)
    return __builtin_amdgcn_perm(__float_as_uint(a), __float_as_uint(b), 0x03020706u);
}
__device__ __forceinline__ unsigned short f2bf(float f) {   // RNE (E setup only)
    unsigned u = __float_as_uint(f);
    u += 0x7fffu + ((u >> 16) & 1u);
    return (unsigned short)(u >> 16);
}
__device__ __forceinline__ float lo16f(unsigned u) { return __uint_as_float(u << 16); }
__device__ __forceinline__ float hi16f(unsigned u) { return __uint_as_float(u & 0xffff0000u); }

#define MFMA16(A, B, C) __builtin_amdgcn_mfma_f32_16x16x32_bf16((A), (B), (C), 0, 0, 0)

// ---------------------------------------------------------------------------
// One fused kernel, 320 threads (5 waves) per block.
// Blocks 0..7  : scan group g. wave0 = MFMA consumer; waves1..4 = loaders
//                (loader w handles steps t ≡ w-1 mod 4) streaming bf16-packed
//                exp(y_pred*mask) (-1 sentinel when masked) into a 4-superslot
//                LDS ring; handshake ONCE PER 8 STEPS via an LDS counter.
// Blocks 8..135: real-path score, 5 waves x 103 rows; atomicAdd(-score).
// ---------------------------------------------------------------------------
__global__ __launch_bounds__(320, 1) void crf_all(
    const float* __restrict__ y_true, const float* __restrict__ y_pred,
    const float* __restrict__ mask, const float* __restrict__ trans,
    float* __restrict__ out)
{
    __shared__ __align__(16) unsigned ring[4][8][1024];  // 128 KB: 4 superslots x 8 steps x 4KB
    __shared__ int cnt[4];
    __shared__ int vcons_s;

    const int tid  = threadIdx.x;
    const int lane = tid & 63;
    const int w    = tid >> 6;

    if (blockIdx.x >= 8) {
        // ===================== real path (R3..R7-verified core) =============
        const int rb  = blockIdx.x - 8;
        const int ts  = w * 103;
        const int te  = min(ts + 103, TT - 1);
        const float* yt_b = y_true + (size_t)rb * TT * CC;
        const float* yp_b = y_pred + (size_t)rb * TT * CC;
        const float* m_b  = mask + (size_t)rb * TT;

        float em = 0.f, tr = 0.f;
        int lprev = 0; float mprev = 0.f;
        const float* ytr = yt_b + ts * CC;
        const float* ypr = yp_b + ts * CC;
        float cyt0 = ytr[lane], cyt1 = ytr[lane + 64];
        float cyp0 = ypr[lane], cyp1 = ypr[lane + 64];
        float cm = m_b[ts];
        for (int t = ts; t <= te; ++t) {
            float nyt0 = 0.f, nyt1 = 0.f, nyp0 = 0.f, nyp1 = 0.f, nm = 0.f;
            if (t < te) {
                const float* ytn = yt_b + (t + 1) * CC;
                const float* ypn = yp_b + (t + 1) * CC;
                nyt0 = ytn[lane]; nyt1 = ytn[lane + 64];
                nyp0 = ypn[lane]; nyp1 = ypn[lane + 64];
                nm = m_b[t + 1];
            }
            unsigned long long b0 = __ballot(cyt0 > 0.5f);
            unsigned long long b1 = __ballot(cyt1 > 0.5f);
            int l = b0 ? (__ffsll(b0) - 1) : (64 + __ffsll(b1) - 1);
            float v0 = __shfl(cyp0, l & 63);
            float v1 = __shfl(cyp1, l & 63);
            float v  = (l < 64) ? v0 : v1;
            if (lane == 0) {
                if (t < ts + 103) em += cm * cm * v;
                if (t > ts)       tr += mprev * cm * trans[lprev * CC + l];
            }
            lprev = l; mprev = cm;
            cyt0 = nyt0; cyt1 = nyt1; cyp0 = nyp0; cyp1 = nyp1; cm = nm;
        }
        if (lane == 0) atomicAdd(&out[rb], -(em + tr));
        return;
    }

    // ========================== scan blocks ==========================
    volatile int* vcnt = cnt;
    volatile int* vcp  = &vcons_s;
    const int g  = blockIdx.x;
    const int bq = lane & 15;
    const int q  = lane >> 4;

    if (w == 0) {
        if (lane < 4)   vcnt[lane] = 0;
        if (lane == 4)  *vcp = -1;
    }
    __syncthreads();   // scan blocks only; all 5 waves reach

    if (w > 0) {
        // ========================== loader wave ==========================
        const int p = w - 1;                        // steps t ≡ p (mod 4)
        const float* ybase = y_pred + (size_t)(g * 16 + bq) * TT * CC;
        const float* mrow  = mask + (size_t)(g * 16 + bq) * TT;

        float4 va[8], vb[8]; float ma, mb = 0.f;
        {
            const float* r = ybase + (size_t)p * CC;
            #pragma unroll
            for (int c = 0; c < 8; ++c)
                va[c] = *(const float4*)(r + ((c >> 1) * 32 + q * 8 + (c & 1) * 4));
            ma = mrow[p];
        }
        for (int t = p; t < TT; t += 4) {
            if (t + 4 < TT) {                       // depth-2 pipeline
                const float* r = ybase + (size_t)(t + 4) * CC;
                #pragma unroll
                for (int c = 0; c < 8; ++c)
                    vb[c] = *(const float4*)(r + ((c >> 1) * 32 + q * 8 + (c & 1) * 4));
                mb = mrow[t + 4];
            }
            const int S = t >> 3;
            while (*vcp < S - 4) __builtin_amdgcn_s_sleep(8);   // ring back-pressure
            const bool live = (ma > 0.f) || (t == 0);
            unsigned pu[16];
            #pragma unroll
            for (int c = 0; c < 8; ++c) {
                float ex, ey, ez, ew;
                if (live) {
                    ex = __expf(va[c].x * ma); ey = __expf(va[c].y * ma);
                    ez = __expf(va[c].z * ma); ew = __expf(va[c].w * ma);
                } else { ex = ey = ez = ew = -1.0f; }
                pu[2 * c + 0] = pk_trunc(ex, ey);
                pu[2 * c + 1] = pk_trunc(ez, ew);
            }
            unsigned* dst = &ring[S & 3][t & 7][0];
            #pragma unroll
            for (int k = 0; k < 4; ++k) {
                u32x4 wv;
                wv[0] = pu[4 * k + 0]; wv[1] = pu[4 * k + 1];
                wv[2] = pu[4 * k + 2]; wv[3] = pu[4 * k + 3];
                *(u32x4*)(dst + k * 256 + lane * 4) = wv;
            }
            __atomic_signal_fence(__ATOMIC_SEQ_CST);      // data before count
            if (lane == 0) atomicAdd((int*)&cnt[S & 3], 1);
            #pragma unroll
            for (int c = 0; c < 8; ++c) va[c] = vb[c];
            ma = mb;
        }
        return;
    }

    // ========================== consumer wave ==========================
    // A-frags: Af[nt][kt] = E^T tile with row perm sigma (R4-verified).
    short8 Af[8][4];
    #pragma unroll
    for (int nt = 0; nt < 8; ++nt) {
        const int j = 32 * (nt & 3) + 8 * (bq >> 2) + 4 * (nt >> 2) + (bq & 3);
        #pragma unroll
        for (int kt = 0; kt < 4; ++kt) {
            #pragma unroll
            for (int e = 0; e < 8; ++e)
                Af[nt][kt][e] = (short)f2bf(__expf(trans[(kt * 32 + q * 8 + e) * CC + j]));
        }
    }

    float pend = 1.f, lacc = 0.f;
    unsigned ps[16];          // packed bf16 state = next-step B-fragments

    auto dostep = [&](const unsigned* src, bool AP, bool RN) {
        u32x4 E[4];
        #pragma unroll
        for (int k = 0; k < 4; ++k)
            E[k] = *(const u32x4*)(src + k * 256 + lane * 4);
        short8 Bf[4];
        #pragma unroll
        for (int kt = 0; kt < 4; ++kt) {
            union { unsigned u[4]; short8 s; } bu;
            bu.u[0] = ps[4 * kt + 0]; bu.u[1] = ps[4 * kt + 1];
            bu.u[2] = ps[4 * kt + 2]; bu.u[3] = ps[4 * kt + 3];
            Bf[kt] = bu.s;
        }
        f32x4 acc[8];
        #pragma unroll
        for (int nt = 0; nt < 8; ++nt) {
            f32x4 a = {0.f, 0.f, 0.f, 0.f};
            a = MFMA16(Af[nt][0], Bf[0], a);
            a = MFMA16(Af[nt][1], Bf[1], a);
            a = MFMA16(Af[nt][2], Bf[2], a);
            a = MFMA16(Af[nt][3], Bf[3], a);
            acc[nt] = a;
        }
        const float mv = lo16f(E[0][0]);        // -1 sentinel = masked step
        float val[8][4];
        #pragma unroll
        for (int nt = 0; nt < 8; ++nt) {
            const int c = 2 * (nt & 3) + (nt >> 2);
            const unsigned plo = E[(2 * c) >> 2][(2 * c) & 3];
            const unsigned phi = E[(2 * c + 1) >> 2][(2 * c + 1) & 3];
            val[nt][0] = acc[nt][0] * lo16f(plo);
            val[nt][1] = acc[nt][1] * hi16f(plo);
            val[nt][2] = acc[nt][2] * lo16f(phi);
            val[nt][3] = acc[nt][3] * hi16f(phi);
            if (AP) {
                val[nt][0] *= pend; val[nt][1] *= pend;
                val[nt][2] *= pend; val[nt][3] *= pend;
            }
        }
        unsigned nps[16];
        #pragma unroll
        for (int nt = 0; nt < 8; ++nt) {
            const int kt = nt & 3, h = nt >> 2;
            nps[kt * 4 + 2 * h + 0] = pk_trunc(val[nt][0], val[nt][1]);
            nps[kt * 4 + 2 * h + 1] = pk_trunc(val[nt][2], val[nt][3]);
        }
        if (__ballot(mv < 0.f)) {               // rare keep-old path
            #pragma unroll
            for (int p2 = 0; p2 < 16; ++p2) {
                unsigned kept = pk_trunc(lo16f(ps[p2]) * pend, hi16f(ps[p2]) * pend);
                nps[p2] = (mv < 0.f) ? kept : nps[p2];
            }
        }
        #pragma unroll
        for (int p2 = 0; p2 < 16; ++p2) ps[p2] = nps[p2];
        if (AP) pend = 1.f;
        if (RN) {
            float s2 = lo16f(ps[0]);
            float bc = __shfl(s2, bq, 64);
            pend = __builtin_amdgcn_rcpf(bc);
            lacc += __logf(bc);
        }
    };

    // -------- superslot 0: t=0 init + steps 1..7 --------
    while (vcnt[0] != 8) __builtin_amdgcn_s_sleep(2);
    __atomic_signal_fence(__ATOMIC_SEQ_CST);
    {
        const unsigned* src = &ring[0][0][0];
        #pragma unroll
        for (int k = 0; k < 4; ++k) {
            u32x4 e0 = *(const u32x4*)(src + k * 256 + lane * 4);
            ps[4 * k + 0] = e0[0]; ps[4 * k + 1] = e0[1];
            ps[4 * k + 2] = e0[2]; ps[4 * k + 3] = e0[3];
        }
    }
    dostep(&ring[0][1][0], true,  false);
    dostep(&ring[0][2][0], false, false);
    dostep(&ring[0][3][0], false, false);
    dostep(&ring[0][4][0], false, true);
    dostep(&ring[0][5][0], true,  false);
    dostep(&ring[0][6][0], false, false);
    dostep(&ring[0][7][0], false, false);
    vcnt[0] = 0;
    __atomic_signal_fence(__ATOMIC_SEQ_CST);
    *vcp = 0;

    // -------- superslots 1..62: 8 steps each --------
    for (int S = 1; S < 63; ++S) {
        const int sl = S & 3;
        while (vcnt[sl] != 8) __builtin_amdgcn_s_sleep(2);
        __atomic_signal_fence(__ATOMIC_SEQ_CST);
        dostep(&ring[sl][0][0], false, true);
        dostep(&ring[sl][1][0], true,  false);
        dostep(&ring[sl][2][0], false, false);
        dostep(&ring[sl][3][0], false, false);
        dostep(&ring[sl][4][0], false, true);
        dostep(&ring[sl][5][0], true,  false);
        dostep(&ring[sl][6][0], false, false);
        dostep(&ring[sl][7][0], false, false);
        vcnt[sl] = 0;
        __atomic_signal_fence(__ATOMIC_SEQ_CST);
        *vcp = S;
    }

    // -------- superslot 63: steps 504..510, then final-sum t=511 --------
    while (vcnt[3] != 8) __builtin_amdgcn_s_sleep(2);
    __atomic_signal_fence(__ATOMIC_SEQ_CST);
    dostep(&ring[3][0][0], false, true);
    dostep(&ring[3][1][0], true,  false);
    dostep(&ring[3][2][0], false, false);
    dostep(&ring[3][3][0], false, false);
    dostep(&ring[3][4][0], false, true);
    dostep(&ring[3][5][0], true,  false);
    dostep(&ring[3][6][0], false, false);
    {
        const unsigned* src = &ring[3][7][0];
        u32x4 E[4];
        #pragma unroll
        for (int k = 0; k < 4; ++k)
            E[k] = *(const u32x4*)(src + k * 256 + lane * 4);
        short8 Bf[4];
        #pragma unroll
        for (int kt = 0; kt < 4; ++kt) {
            union { unsigned u[4]; short8 s; } bu;
            bu.u[0] = ps[4 * kt + 0]; bu.u[1] = ps[4 * kt + 1];
            bu.u[2] = ps[4 * kt + 2]; bu.u[3] = ps[4 * kt + 3];
            Bf[kt] = bu.s;
        }
        float ssum = 0.f;
        const float mv = lo16f(E[0][0]);
        #pragma unroll
        for (int nt = 0; nt < 8; ++nt) {
            f32x4 a = {0.f, 0.f, 0.f, 0.f};
            a = MFMA16(Af[nt][0], Bf[0], a);
            a = MFMA16(Af[nt][1], Bf[1], a);
            a = MFMA16(Af[nt][2], Bf[2], a);
            a = MFMA16(Af[nt][3], Bf[3], a);
            const int c = 2 * (nt & 3) + (nt >> 2);
            const unsigned plo = E[(2 * c) >> 2][(2 * c) & 3];
            const unsigned phi = E[(2 * c + 1) >> 2][(2 * c + 1) & 3];
            ssum += a[0] * lo16f(plo) + a[1] * hi16f(plo)
                  + a[2] * lo16f(phi) + a[3] * hi16f(phi);
        }
        if (__ballot(mv < 0.f)) {
            float os = 0.f;
            #pragma unroll
            for (int p2 = 0; p2 < 16; ++p2) os += lo16f(ps[p2]) + hi16f(ps[p2]);
            ssum = (mv < 0.f) ? os : ssum;   // pend == 1 here (511 % 4 == 3)
        }
        ssum += __shfl_xor(ssum, 16, 64);
        ssum += __shfl_xor(ssum, 32, 64);
        if (lane < 16) atomicAdd(&out[g * 16 + lane], __logf(ssum) + lacc);
    }
}

// ---------------------------------------------------------------------------
extern "C" void kernel_launch(void* const* d_in, const int* in_sizes, int n_in,
                              void* d_out, int out_size, void* d_ws, size_t ws_size,
                              hipStream_t stream) {
    (void)in_sizes; (void)n_in; (void)out_size; (void)d_ws; (void)ws_size;
    const float* y_true = (const float*)d_in[0];
    const float* y_pred = (const float*)d_in[1];
    const float* mask   = (const float*)d_in[2];
    const float* trans  = (const float*)d_in[3];
    float* out = (float*)d_out;

    hipMemsetAsync(out, 0, BB * sizeof(float), stream);
    crf_all<<<dim3(8 + BB), 320, 0, stream>>>(y_true, y_pred, mask, trans, out);
}